// Round 1
// baseline (382.571 us; speedup 1.0000x reference)
//
#include <hip/hip_runtime.h>

// Problem constants (from reference): images (16,3,768,768) f32,
// h=w=48, N=2304, SIGMA_COLOR=0.1 -> exp(-50*cd), SIGMA_SPATIAL=5 -> exp(-0.02*sd), RADIUS=8.
#define BATCH 16
#define CH    3
#define HIN   768
#define WIN   768
#define HS    48
#define WS    48
#define NPIX  (HS * WS)          // 2304
#define QPR   (NPIX / 4)         // 576 float4 quads per output row

// Kernel 1: bilinear downsample 768->48 (half-pixel centers, scale 16).
// Output coord for index i is 16*i + 7.5 -> exact average of pixels {16i+7, 16i+8}
// in each axis, i.e. a 2x2 average. One thread per (b, n); writes float4 (c0,c1,c2,0).
__global__ void downsample_kernel(const float* __restrict__ img,
                                  float4* __restrict__ feats) {
    int idx = blockIdx.x * blockDim.x + threadIdx.x;   // over BATCH*NPIX = 36864
    if (idx >= BATCH * NPIX) return;
    int b = idx / NPIX;
    int n = idx - b * NPIX;
    int y = n / WS;
    int x = n - y * WS;
    int iy = 16 * y + 7;
    int ix = 16 * x + 7;
    const float* base = img + (size_t)b * CH * HIN * WIN;
    float f[3];
#pragma unroll
    for (int c = 0; c < 3; ++c) {
        const float* p = base + (size_t)c * HIN * WIN;
        const float* r0 = p + (size_t)iy * WIN + ix;
        const float* r1 = r0 + WIN;
        // 4*(16x+7) = 64x+28 is only 4B-aligned -> scalar loads (kernel is tiny anyway)
        f[c] = 0.25f * (r0[0] + r0[1] + r1[0] + r1[1]);
    }
    feats[idx] = make_float4(f[0], f[1], f[2], 0.0f);
}

// Kernel 2: out[b][i][j] = mask(|dy|<=8,|dx|<=8) * exp(-50*||fi-fj||^2 - 0.02*(dy^2+dx^2))
// One thread per output float4 (4 consecutive j). 48%4==0 so a quad stays in one
// j-grid-row -> single dy test per quad; |dy|>8 (~65% of quads) stores zeros w/o loads.
__global__ void affinity_kernel(const float4* __restrict__ feats,
                                float4* __restrict__ out) {
    unsigned int t = blockIdx.x * blockDim.x + threadIdx.x;  // quad id < 21,233,664
    const unsigned int total = (unsigned int)BATCH * NPIX * QPR;
    if (t >= total) return;

    unsigned int q  = t % QPR;        // quad within the j dimension
    unsigned int bi = t / QPR;        // b*NPIX + i
    unsigned int i  = bi % NPIX;
    unsigned int b  = bi / NPIX;

    int j0  = (int)q * 4;
    int yj  = j0 / WS;
    int xj0 = j0 - yj * WS;
    int yi  = (int)i / WS;
    int xi  = (int)i - yi * WS;

    int dy = yi - yj;
    float4 res;
    if (dy > 8 || dy < -8) {
        res = make_float4(0.f, 0.f, 0.f, 0.f);
    } else {
        const float4* frow = feats + (size_t)b * NPIX;
        float4 fi = frow[i];
        float sdy = (float)(dy * dy);
        float v[4];
#pragma unroll
        for (int k = 0; k < 4; ++k) {
            int dx = xi - (xj0 + k);
            float4 fj = frow[j0 + k];
            float d0 = fi.x - fj.x;
            float d1 = fi.y - fj.y;
            float d2 = fi.z - fj.z;
            float cd = d0 * d0 + d1 * d1 + d2 * d2;
            float sd = sdy + (float)(dx * dx);
            float e  = __expf(-50.0f * cd - 0.02f * sd);
            v[k] = (dx > 8 || dx < -8) ? 0.0f : e;
        }
        res = make_float4(v[0], v[1], v[2], v[3]);
    }
    out[(size_t)t] = res;
}

extern "C" void kernel_launch(void* const* d_in, const int* in_sizes, int n_in,
                              void* d_out, int out_size, void* d_ws, size_t ws_size,
                              hipStream_t stream) {
    const float* img = (const float*)d_in[0];
    float4* feats = (float4*)d_ws;                 // needs 16*2304*16 B = 589,824 B
    float4* out   = (float4*)d_out;                // 16*2304*2304 floats

    {
        int threads = BATCH * NPIX;                // 36,864
        int block = 256;
        int grid = (threads + block - 1) / block;  // 144
        downsample_kernel<<<grid, block, 0, stream>>>(img, feats);
    }
    {
        unsigned int quads = (unsigned int)BATCH * NPIX * QPR;  // 21,233,664
        int block = 256;
        unsigned int grid = (quads + block - 1) / block;        // 82,944
        affinity_kernel<<<grid, block, 0, stream>>>(feats, out);
    }
}